// Round 1
// baseline (4997.906 us; speedup 1.0000x reference)
//
#include <hip/hip_runtime.h>
#include <math.h>

#define NPOP 65536
#define H    2048
#define HH   1024
#define KSEL 50

// ---------------- mask dtype detection ----------------
// flag: 0 = int32 (0/1), 1 = byte bool, 2 = float32 (0.0/1.0)
__global__ void k_maskdetect(const unsigned int* __restrict__ m, int* __restrict__ flag) {
    __shared__ int sfloat, sbyte;
    if (threadIdx.x == 0) { sfloat = 0; sbyte = 0; }
    __syncthreads();
    // examine first 102400 bytes = 25600 dwords (safe for all 3 dtypes)
    for (int i = threadIdx.x; i < 25600; i += 256) {
        unsigned int v = m[i];
        if (v == 0x3F800000u) sfloat = 1;
        else if (v & 0xFFFFFF00u) sbyte = 1;
    }
    __syncthreads();
    if (threadIdx.x == 0) *flag = sfloat ? 2 : (sbyte ? 1 : 0);
}

// ---------------- fitness GEMM (fused relu + w2 dot) ----------------
// grid (8, 512): x = col chunk (8 x 128 of HH), y = row block (512 x 128)
// writes xpart[row*8 + nb] = sum_{cols in chunk} relu(pop@w1 + b1)[row,c] * w2[c]
__global__ __launch_bounds__(256) void k_fit_gemm(
    const float* __restrict__ pop, const float* __restrict__ w1,
    const float* __restrict__ bias1, const float* __restrict__ w2,
    float* __restrict__ xpart)
{
    __shared__ float As[16][128];   // [k][row]
    __shared__ float Bs[16][128];   // [k][col]
    const int nb   = blockIdx.x;
    const int row0 = blockIdx.y * 128;
    const int col0 = nb * 128;
    const int t  = threadIdx.x;
    const int tx = t & 15;    // col group
    const int ty = t >> 4;    // row group

    float acc[8][8];
#pragma unroll
    for (int i = 0; i < 8; ++i)
#pragma unroll
        for (int j = 0; j < 8; ++j) acc[i][j] = 0.f;

    const int lr = t >> 1;         // A load row 0..127
    const int lk = (t & 1) * 8;    // A load k offset 0/8
    const int bk = t >> 4;         // B load k 0..15
    const int bc = (t & 15) * 8;   // B load col offset

    for (int k0 = 0; k0 < H; k0 += 16) {
        const float4 a0 = *(const float4*)(pop + (size_t)(row0 + lr) * H + k0 + lk);
        const float4 a1 = *(const float4*)(pop + (size_t)(row0 + lr) * H + k0 + lk + 4);
        const float4 c0 = *(const float4*)(w1 + (size_t)(k0 + bk) * HH + col0 + bc);
        const float4 c1 = *(const float4*)(w1 + (size_t)(k0 + bk) * HH + col0 + bc + 4);
        __syncthreads();
        As[lk + 0][lr] = a0.x; As[lk + 1][lr] = a0.y; As[lk + 2][lr] = a0.z; As[lk + 3][lr] = a0.w;
        As[lk + 4][lr] = a1.x; As[lk + 5][lr] = a1.y; As[lk + 6][lr] = a1.z; As[lk + 7][lr] = a1.w;
        *(float4*)&Bs[bk][bc]     = c0;
        *(float4*)&Bs[bk][bc + 4] = c1;
        __syncthreads();
#pragma unroll
        for (int kk = 0; kk < 16; ++kk) {
            const float4 ra0 = *(const float4*)&As[kk][ty * 8];
            const float4 ra1 = *(const float4*)&As[kk][ty * 8 + 4];
            const float4 rb0 = *(const float4*)&Bs[kk][tx * 8];
            const float4 rb1 = *(const float4*)&Bs[kk][tx * 8 + 4];
            const float av[8] = {ra0.x, ra0.y, ra0.z, ra0.w, ra1.x, ra1.y, ra1.z, ra1.w};
            const float bv[8] = {rb0.x, rb0.y, rb0.z, rb0.w, rb1.x, rb1.y, rb1.z, rb1.w};
#pragma unroll
            for (int i = 0; i < 8; ++i)
#pragma unroll
                for (int j = 0; j < 8; ++j)
                    acc[i][j] = fmaf(av[i], bv[j], acc[i][j]);
        }
    }

    // epilogue: relu + dot with w2 chunk, reduce across tx (16 lanes)
    float part[8];
#pragma unroll
    for (int i = 0; i < 8; ++i) part[i] = 0.f;
#pragma unroll
    for (int j = 0; j < 8; ++j) {
        const int c = col0 + tx * 8 + j;
        const float bb = bias1[c];
        const float ww = w2[c];
#pragma unroll
        for (int i = 0; i < 8; ++i) {
            float h = acc[i][j] + bb;
            h = fmaxf(h, 0.f);
            part[i] = fmaf(h, ww, part[i]);
        }
    }
#pragma unroll
    for (int m = 1; m <= 8; m <<= 1)
#pragma unroll
        for (int i = 0; i < 8; ++i) part[i] += __shfl_xor(part[i], m);
    if (tx == 0) {
#pragma unroll
        for (int i = 0; i < 8; ++i)
            xpart[(size_t)(row0 + ty * 8 + i) * 8 + nb] = part[i];
    }
}

// ---------------- fitness finish: sum partials + sigmoid ----------------
__global__ void k_fit_finish(const float* __restrict__ xpart,
                             const float* __restrict__ b2,
                             float* __restrict__ fit)
{
    const int i = blockIdx.x * 256 + threadIdx.x;
    if (i >= NPOP) return;
    float s = b2[0];
#pragma unroll
    for (int nb = 0; nb < 8; ++nb) s += xpart[(size_t)i * 8 + nb];
    fit[i] = 1.f / (1.f + expf(-s));
}

// ---------------- top-50 (sequential argmax, tie -> lower index) ----------------
__global__ __launch_bounds__(1024) void k_topk(const float* __restrict__ fit,
                                               int* __restrict__ best)
{
    __shared__ unsigned long long keys[1024];
    __shared__ unsigned int taken[NPOP / 32];   // 8 KB bitmask
    const int t = threadIdx.x;
    for (int i = t; i < NPOP / 32; i += 1024) taken[i] = 0u;
    __syncthreads();
    for (int r = 0; r < KSEL; ++r) {
        unsigned long long lk = 0ull;
        for (int i = t; i < NPOP; i += 1024) {
            if (taken[i >> 5] & (1u << (i & 31))) continue;
            const unsigned int fv = __float_as_uint(fit[i]); // fit>0 -> uint order == float order
            const unsigned long long key =
                ((unsigned long long)fv << 32) | (unsigned int)(~i);
            if (key > lk) lk = key;
        }
        keys[t] = lk;
        __syncthreads();
        for (int s = 512; s > 0; s >>= 1) {
            if (t < s) { if (keys[t + s] > keys[t]) keys[t] = keys[t + s]; }
            __syncthreads();
        }
        if (t == 0) {
            const unsigned long long kk = keys[0];
            const int idx = (int)(~(unsigned int)kk);
            best[r] = idx;
            taken[idx >> 5] |= (1u << (idx & 31));
        }
        __syncthreads();
    }
}

// ---------------- mutation layer 1: mid = gelu(best @ mut_w1 + mut_b1) ----------------
// grid 32 blocks x 256 threads; block covers all 50 rows x 64 cols
__global__ __launch_bounds__(256) void k_mut1(
    const float* __restrict__ pop, const int* __restrict__ best,
    const float* __restrict__ w, const float* __restrict__ b,
    float* __restrict__ mid)
{
    __shared__ float As[KSEL][32];
    __shared__ float Bs[32][64];
    __shared__ int sidx[KSEL];
    const int t = threadIdx.x;
    if (t < KSEL) sidx[t] = best[t];
    __syncthreads();
    const int col0 = blockIdx.x * 64;
    const int c  = t & 63;
    const int rg = t >> 6;   // wave id 0..3
    float acc[13];
#pragma unroll
    for (int m = 0; m < 13; ++m) acc[m] = 0.f;

    for (int k0 = 0; k0 < H; k0 += 32) {
        __syncthreads();
        for (int e = t; e < KSEL * 32; e += 256) {
            const int r = e >> 5, k = e & 31;
            As[r][k] = pop[(size_t)sidx[r] * H + k0 + k];
        }
        for (int e = t; e < 32 * 64; e += 256) {
            const int k = e >> 6, cc = e & 63;
            Bs[k][cc] = w[(size_t)(k0 + k) * H + col0 + cc];
        }
        __syncthreads();
#pragma unroll
        for (int k4 = 0; k4 < 8; ++k4) {
            float bv0 = Bs[k4 * 4 + 0][c];
            float bv1 = Bs[k4 * 4 + 1][c];
            float bv2 = Bs[k4 * 4 + 2][c];
            float bv3 = Bs[k4 * 4 + 3][c];
#pragma unroll
            for (int m = 0; m < 13; ++m) {
                const int r = rg + m * 4;
                if (r < KSEL) {
                    const float4 av = *(const float4*)&As[r][k4 * 4];
                    acc[m] = fmaf(av.x, bv0, acc[m]);
                    acc[m] = fmaf(av.y, bv1, acc[m]);
                    acc[m] = fmaf(av.z, bv2, acc[m]);
                    acc[m] = fmaf(av.w, bv3, acc[m]);
                }
            }
        }
    }
#pragma unroll
    for (int m = 0; m < 13; ++m) {
        const int r = rg + m * 4;
        if (r < KSEL) {
            const int col = col0 + c;
            const float v = acc[m] + b[col];
            const float g = 0.5f * v * (1.f + erff(v * 0.70710678118654752f));
            mid[(size_t)r * H + col] = g;
        }
    }
}

// ---------------- mutation layer 2 + crossover ----------------
__global__ __launch_bounds__(256) void k_mut2(
    const float* __restrict__ mid, const float* __restrict__ w,
    const float* __restrict__ b, const float* __restrict__ pop,
    const int* __restrict__ best, const void* __restrict__ mask,
    const int* __restrict__ mflag, float* __restrict__ out)
{
    __shared__ float As[KSEL][32];
    __shared__ float Bs[32][64];
    __shared__ int sidx[KSEL];
    const int t = threadIdx.x;
    if (t < KSEL) sidx[t] = best[t];
    __syncthreads();
    const int col0 = blockIdx.x * 64;
    const int c  = t & 63;
    const int rg = t >> 6;
    const int mf = *mflag;
    float acc[13];
#pragma unroll
    for (int m = 0; m < 13; ++m) acc[m] = 0.f;

    for (int k0 = 0; k0 < H; k0 += 32) {
        __syncthreads();
        for (int e = t; e < KSEL * 32; e += 256) {
            const int r = e >> 5, k = e & 31;
            As[r][k] = mid[(size_t)r * H + k0 + k];
        }
        for (int e = t; e < 32 * 64; e += 256) {
            const int k = e >> 6, cc = e & 63;
            Bs[k][cc] = w[(size_t)(k0 + k) * H + col0 + cc];
        }
        __syncthreads();
#pragma unroll
        for (int k4 = 0; k4 < 8; ++k4) {
            float bv0 = Bs[k4 * 4 + 0][c];
            float bv1 = Bs[k4 * 4 + 1][c];
            float bv2 = Bs[k4 * 4 + 2][c];
            float bv3 = Bs[k4 * 4 + 3][c];
#pragma unroll
            for (int m = 0; m < 13; ++m) {
                const int r = rg + m * 4;
                if (r < KSEL) {
                    const float4 av = *(const float4*)&As[r][k4 * 4];
                    acc[m] = fmaf(av.x, bv0, acc[m]);
                    acc[m] = fmaf(av.y, bv1, acc[m]);
                    acc[m] = fmaf(av.z, bv2, acc[m]);
                    acc[m] = fmaf(av.w, bv3, acc[m]);
                }
            }
        }
    }
#pragma unroll
    for (int m = 0; m < 13; ++m) {
        const int r = rg + m * 4;
        if (r < KSEL) {
            const int col = col0 + c;
            const size_t mi = (size_t)r * H + col;
            const float v = acc[m] + b[col];
            bool mv;
            if (mf == 2)      mv = ((const float*)mask)[mi] != 0.f;
            else if (mf == 1) mv = ((const unsigned char*)mask)[mi] != 0;
            else              mv = ((const int*)mask)[mi] != 0;
            const float bestv = pop[(size_t)sidx[r] * H + col];
            out[mi] = mv ? bestv : v;
        }
    }
}

extern "C" void kernel_launch(void* const* d_in, const int* in_sizes, int n_in,
                              void* d_out, int out_size, void* d_ws, size_t ws_size,
                              hipStream_t stream) {
    const float* pop = (const float*)d_in[0];
    const float* sw1 = (const float*)d_in[1];
    const float* sb1 = (const float*)d_in[2];
    const float* sw2 = (const float*)d_in[3];
    const float* sb2 = (const float*)d_in[4];
    const float* mw1 = (const float*)d_in[5];
    const float* mb1 = (const float*)d_in[6];
    const float* mw2 = (const float*)d_in[7];
    const float* mb2 = (const float*)d_in[8];
    const void*  mask = d_in[9];

    float* out_off = (float*)d_out;                      // offspring [50*2048]
    float* out_fit = (float*)d_out + (size_t)KSEL * H;   // fitness  [65536]

    char* ws = (char*)d_ws;
    float* xpart = (float*)ws;                                   // 65536*8 f32 = 2 MB
    int*   best  = (int*)(ws + (size_t)NPOP * 8 * 4);            // 64 ints
    int*   mflag = (int*)(ws + (size_t)NPOP * 8 * 4 + 256);      // 1 int
    float* mid   = (float*)(ws + (size_t)NPOP * 8 * 4 + 512);    // 50*2048 f32

    hipLaunchKernelGGL(k_maskdetect, dim3(1), dim3(256), 0, stream,
                       (const unsigned int*)mask, mflag);
    hipLaunchKernelGGL(k_fit_gemm, dim3(8, 512), dim3(256), 0, stream,
                       pop, sw1, sb1, sw2, xpart);
    hipLaunchKernelGGL(k_fit_finish, dim3(NPOP / 256), dim3(256), 0, stream,
                       xpart, sb2, out_fit);
    hipLaunchKernelGGL(k_topk, dim3(1), dim3(1024), 0, stream, out_fit, best);
    hipLaunchKernelGGL(k_mut1, dim3(H / 64), dim3(256), 0, stream,
                       pop, best, mw1, mb1, mid);
    hipLaunchKernelGGL(k_mut2, dim3(H / 64), dim3(256), 0, stream,
                       mid, mw2, mb2, pop, best, mask, mflag, out_off);
}

// Round 2
// 1627.792 us; speedup vs baseline: 3.0704x; 3.0704x over previous
//
#include <hip/hip_runtime.h>
#include <math.h>

#define NPOP 65536
#define H    2048
#define HH   1024
#define KSEL 50

using bf16x8 = __attribute__((ext_vector_type(8))) short;
using f32x4  = __attribute__((ext_vector_type(4))) float;

__device__ __forceinline__ unsigned short f2bf(float x) {
    unsigned u = __float_as_uint(x);
    return (unsigned short)((u + 0x7FFFu + ((u >> 16) & 1u)) >> 16);
}

// ---------------- mask dtype detection ----------------
__global__ void k_maskdetect(const unsigned int* __restrict__ m, int* __restrict__ flag) {
    __shared__ int sfloat, sbyte;
    if (threadIdx.x == 0) { sfloat = 0; sbyte = 0; }
    __syncthreads();
    for (int i = threadIdx.x; i < 25600; i += 256) {
        unsigned int v = m[i];
        if (v == 0x3F800000u) sfloat = 1;
        else if (v & 0xFFFFFF00u) sbyte = 1;
    }
    __syncthreads();
    if (threadIdx.x == 0) *flag = sfloat ? 2 : (sbyte ? 1 : 0);
}

// ---------------- W1 transpose + bf16 hi/lo split ----------------
// w1 [2048][1024] f32 -> w1t_hi/lo [1024][2048] bf16 bits
__global__ __launch_bounds__(256) void k_w1split(
    const float* __restrict__ w1,
    unsigned short* __restrict__ th, unsigned short* __restrict__ tl)
{
    __shared__ float tile[64][65];
    const int t = threadIdx.x;
    const int n0 = blockIdx.x * 64;
    const int k0 = blockIdx.y * 64;
#pragma unroll
    for (int p = 0; p < 4; ++p) {
        const int kr = (t >> 4) + p * 16;
        const int nc = (t & 15) * 4;
        const float4 v = *(const float4*)&w1[(size_t)(k0 + kr) * HH + n0 + nc];
        tile[kr][nc] = v.x; tile[kr][nc + 1] = v.y; tile[kr][nc + 2] = v.z; tile[kr][nc + 3] = v.w;
    }
    __syncthreads();
#pragma unroll
    for (int p = 0; p < 4; ++p) {
        const int nr = (t >> 4) + p * 16;
        const int kc = (t & 15) * 4;
        unsigned hh[4], ll[4];
#pragma unroll
        for (int e = 0; e < 4; ++e) {
            const float x = tile[kc + e][nr];
            const unsigned short hb = f2bf(x);
            const float hf = __uint_as_float((unsigned)hb << 16);
            hh[e] = hb;
            ll[e] = f2bf(x - hf);
        }
        uint2 ph, pl;
        ph.x = hh[0] | (hh[1] << 16); ph.y = hh[2] | (hh[3] << 16);
        pl.x = ll[0] | (ll[1] << 16); pl.y = ll[2] | (ll[3] << 16);
        *(uint2*)&th[(size_t)(n0 + nr) * H + k0 + kc] = ph;
        *(uint2*)&tl[(size_t)(n0 + nr) * H + k0 + kc] = pl;
    }
}

// ---------------- fitness GEMM via 3-term bf16-split MFMA ----------------
// grid (8 colblocks, 512 rowblocks), 256 threads (4 waves, 2m x 2n).
// Block tile 128 rows x 128 cols, BK=64. Fused relu + w2-dot epilogue.
__global__ __launch_bounds__(256) void k_fit_mfma(
    const float* __restrict__ pop,
    const unsigned short* __restrict__ w1h, const unsigned short* __restrict__ w1l,
    const float* __restrict__ bias1, const float* __restrict__ w2,
    float* __restrict__ xpart)
{
    __shared__ unsigned short Ah[128 * 64];
    __shared__ unsigned short Al[128 * 64];
    __shared__ unsigned short Bh[128 * 64];
    __shared__ unsigned short Bl[128 * 64];
    const int t = threadIdx.x;
    const int lane = t & 63;
    const int wid = t >> 6;
    const int wm = wid >> 1, wn = wid & 1;
    const int row0 = blockIdx.y * 128;
    const int nb = blockIdx.x;
    const int col0 = nb * 128;

    f32x4 acc[4][4];
#pragma unroll
    for (int i = 0; i < 4; ++i)
#pragma unroll
        for (int j = 0; j < 4; ++j) { f32x4 z = {0.f, 0.f, 0.f, 0.f}; acc[i][j] = z; }

    // LDS fragment read offsets (elements) for kk=0; kk=1 is XOR 32.
    int aoff[4], boff[4];
#pragma unroll
    for (int i = 0; i < 4; ++i) {
        const int ra = wm * 64 + i * 16 + (lane & 15);
        aoff[i] = ra * 64 + (((lane >> 4) ^ (ra & 7)) * 8);
        const int rb = wn * 64 + i * 16 + (lane & 15);
        boff[i] = rb * 64 + (((lane >> 4) ^ (rb & 7)) * 8);
    }
    // staging: thread t covers rows (t>>3)+32q, 8-elem chunk (t&7)
    int woff[4];
#pragma unroll
    for (int q = 0; q < 4; ++q) {
        const int r = (t >> 3) + 32 * q;
        woff[q] = r * 64 + (((t & 7) ^ (r & 7)) * 8);
    }
    const float* asrc = pop + (size_t)(row0 + (t >> 3)) * H + (t & 7) * 8;
    const unsigned short* bsh = w1h + (size_t)(col0 + (t >> 3)) * H + (t & 7) * 8;
    const unsigned short* bsl = w1l + (size_t)(col0 + (t >> 3)) * H + (t & 7) * 8;

    for (int k0 = 0; k0 < H; k0 += 64) {
        __syncthreads();   // previous iter's LDS reads complete
#pragma unroll
        for (int q = 0; q < 4; ++q) {
            const float* s = asrc + (size_t)(32 * q) * H + k0;
            const float4 a0 = *(const float4*)s;
            const float4 a1 = *(const float4*)(s + 4);
            const float xs[8] = {a0.x, a0.y, a0.z, a0.w, a1.x, a1.y, a1.z, a1.w};
            bf16x8 hv, lv;
#pragma unroll
            for (int e = 0; e < 8; ++e) {
                const unsigned short hb = f2bf(xs[e]);
                const float hf = __uint_as_float((unsigned)hb << 16);
                hv[e] = (short)hb;
                lv[e] = (short)f2bf(xs[e] - hf);
            }
            *(bf16x8*)&Ah[woff[q]] = hv;
            *(bf16x8*)&Al[woff[q]] = lv;
            *(bf16x8*)&Bh[woff[q]] = *(const bf16x8*)(bsh + (size_t)(32 * q) * H + k0);
            *(bf16x8*)&Bl[woff[q]] = *(const bf16x8*)(bsl + (size_t)(32 * q) * H + k0);
        }
        __syncthreads();
#pragma unroll
        for (int kk = 0; kk < 2; ++kk) {
            const int x = kk * 32;
            bf16x8 ah[4], al[4], bh[4], bl[4];
#pragma unroll
            for (int i = 0; i < 4; ++i) {
                ah[i] = *(const bf16x8*)&Ah[aoff[i] ^ x];
                al[i] = *(const bf16x8*)&Al[aoff[i] ^ x];
                bh[i] = *(const bf16x8*)&Bh[boff[i] ^ x];
                bl[i] = *(const bf16x8*)&Bl[boff[i] ^ x];
            }
#pragma unroll
            for (int i = 0; i < 4; ++i)
#pragma unroll
                for (int j = 0; j < 4; ++j) {
                    acc[i][j] = __builtin_amdgcn_mfma_f32_16x16x32_bf16(ah[i], bh[j], acc[i][j], 0, 0, 0);
                    acc[i][j] = __builtin_amdgcn_mfma_f32_16x16x32_bf16(ah[i], bl[j], acc[i][j], 0, 0, 0);
                    acc[i][j] = __builtin_amdgcn_mfma_f32_16x16x32_bf16(al[i], bh[j], acc[i][j], 0, 0, 0);
                }
        }
    }

    // epilogue: relu + w2 dot, reduce over 16 cols x 4 j-frags
    float part[4][4];
#pragma unroll
    for (int i = 0; i < 4; ++i)
#pragma unroll
        for (int rg = 0; rg < 4; ++rg) part[i][rg] = 0.f;
#pragma unroll
    for (int j = 0; j < 4; ++j) {
        const int col = col0 + wn * 64 + j * 16 + (lane & 15);
        const float b1c = bias1[col];
        const float w2c = w2[col];
#pragma unroll
        for (int i = 0; i < 4; ++i)
#pragma unroll
            for (int rg = 0; rg < 4; ++rg) {
                float hval = acc[i][j][rg] + b1c;
                hval = fmaxf(hval, 0.f);
                part[i][rg] = fmaf(hval, w2c, part[i][rg]);
            }
    }
#pragma unroll
    for (int m = 1; m <= 8; m <<= 1)
#pragma unroll
        for (int i = 0; i < 4; ++i)
#pragma unroll
            for (int rg = 0; rg < 4; ++rg)
                part[i][rg] += __shfl_xor(part[i][rg], m);
    if ((lane & 15) == 0) {
#pragma unroll
        for (int i = 0; i < 4; ++i)
#pragma unroll
            for (int rg = 0; rg < 4; ++rg) {
                const int row = row0 + wm * 64 + i * 16 + (lane >> 4) * 4 + rg;
                xpart[(size_t)row * 16 + nb * 2 + wn] = part[i][rg];
            }
    }
}

__global__ void k_fit_finish16(const float* __restrict__ xpart,
                               const float* __restrict__ b2, float* __restrict__ fit)
{
    const int i = blockIdx.x * 256 + threadIdx.x;
    if (i >= NPOP) return;
    float s = b2[0];
#pragma unroll
    for (int c = 0; c < 16; ++c) s += xpart[(size_t)i * 16 + c];
    fit[i] = 1.f / (1.f + expf(-s));
}

// ---------------- top-50: cached slice maxima ----------------
__global__ __launch_bounds__(1024) void k_topk2(const float* __restrict__ fit,
                                                int* __restrict__ best)
{
    __shared__ unsigned long long skey[1024];
    __shared__ unsigned long long wred[16];
    __shared__ unsigned int taken[NPOP / 32];
    __shared__ int brd;
    const int t = threadIdx.x;
    for (int i = t; i < NPOP / 32; i += 1024) taken[i] = 0u;
    unsigned long long k = 0ull;
    for (int i = 0; i < 64; ++i) {
        const int idx = t + (i << 10);
        const unsigned fv = __float_as_uint(fit[idx]);
        const unsigned long long key = ((unsigned long long)fv << 32) | (unsigned)(~(unsigned)idx);
        if (key > k) k = key;
    }
    skey[t] = k;
    __syncthreads();
    for (int r = 0; r < KSEL; ++r) {
        unsigned long long v = skey[t];
#pragma unroll
        for (int m = 32; m >= 1; m >>= 1) {
            const unsigned long long o = __shfl_xor(v, m);
            if (o > v) v = o;
        }
        if ((t & 63) == 0) wred[t >> 6] = v;
        __syncthreads();
        if (t == 0) {
            unsigned long long b = wred[0];
#pragma unroll
            for (int w = 1; w < 16; ++w) if (wred[w] > b) b = wred[w];
            const int idx = (int)(~(unsigned)(b & 0xFFFFFFFFull));
            best[r] = idx;
            taken[idx >> 5] |= (1u << (idx & 31));
            brd = idx;
        }
        __syncthreads();
        const int s = brd & 1023;
        if (t == s) {
            unsigned long long k2 = 0ull;
            for (int i = 0; i < 64; ++i) {
                const int idx = s + (i << 10);
                if (taken[idx >> 5] & (1u << (idx & 31))) continue;
                const unsigned fv = __float_as_uint(fit[idx]);
                const unsigned long long key = ((unsigned long long)fv << 32) | (unsigned)(~(unsigned)idx);
                if (key > k2) k2 = key;
            }
            skey[s] = k2;
        }
        __syncthreads();
    }
}

// ---------------- gather best rows ----------------
__global__ void k_gather(const float* __restrict__ pop, const int* __restrict__ best,
                         float* __restrict__ bp)
{
    const int i = blockIdx.x * 256 + threadIdx.x;
    if (i >= KSEL * H) return;
    const int r = i >> 11, c = i & 2047;
    bp[i] = pop[(size_t)best[r] * H + c];
}

// ---------------- mutation partial GEMM (split-K x4) ----------------
// grid (32 colblocks, 4 kchunks), 256 threads. part[ks][50][2048], no bias.
__global__ __launch_bounds__(256) void k_mutp(
    const float* __restrict__ A, const float* __restrict__ W, float* __restrict__ part)
{
    __shared__ float As[KSEL][32];
    __shared__ float Bs[32][64];
    const int t = threadIdx.x;
    const int col0 = blockIdx.x * 64;
    const int kbeg = blockIdx.y * 512;
    const int c = t & 63;
    const int rg = t >> 6;
    float acc[13];
#pragma unroll
    for (int m = 0; m < 13; ++m) acc[m] = 0.f;

    for (int k0 = kbeg; k0 < kbeg + 512; k0 += 32) {
        __syncthreads();
        for (int e = t; e < KSEL * 32; e += 256) {
            const int r = e >> 5, kk = e & 31;
            As[r][kk] = A[(size_t)r * H + k0 + kk];
        }
        for (int e = t; e < 32 * 64; e += 256) {
            const int kk = e >> 6, cc = e & 63;
            Bs[kk][cc] = W[(size_t)(k0 + kk) * H + col0 + cc];
        }
        __syncthreads();
#pragma unroll
        for (int k4 = 0; k4 < 8; ++k4) {
            const float bv0 = Bs[k4 * 4 + 0][c];
            const float bv1 = Bs[k4 * 4 + 1][c];
            const float bv2 = Bs[k4 * 4 + 2][c];
            const float bv3 = Bs[k4 * 4 + 3][c];
#pragma unroll
            for (int m = 0; m < 13; ++m) {
                const int r = rg + m * 4;
                if (r < KSEL) {
                    const float4 av = *(const float4*)&As[r][k4 * 4];
                    acc[m] = fmaf(av.x, bv0, acc[m]);
                    acc[m] = fmaf(av.y, bv1, acc[m]);
                    acc[m] = fmaf(av.z, bv2, acc[m]);
                    acc[m] = fmaf(av.w, bv3, acc[m]);
                }
            }
        }
    }
#pragma unroll
    for (int m = 0; m < 13; ++m) {
        const int r = rg + m * 4;
        if (r < KSEL)
            part[((size_t)blockIdx.y * KSEL + r) * H + col0 + c] = acc[m];
    }
}

__global__ void k_mut1c(const float* __restrict__ part, const float* __restrict__ b,
                        float* __restrict__ mid)
{
    const int i = blockIdx.x * 256 + threadIdx.x;
    if (i >= KSEL * H) return;
    const int c = i & 2047;
    float s = part[i] + part[i + KSEL * H] + part[i + 2 * KSEL * H] + part[i + 3 * KSEL * H];
    const float v = s + b[c];
    mid[i] = 0.5f * v * (1.f + erff(v * 0.70710678118654752f));
}

__global__ void k_mut2c(const float* __restrict__ part, const float* __restrict__ b,
                        const float* __restrict__ bp, const void* __restrict__ mask,
                        const int* __restrict__ mflag, float* __restrict__ out)
{
    const int i = blockIdx.x * 256 + threadIdx.x;
    if (i >= KSEL * H) return;
    const int c = i & 2047;
    float s = part[i] + part[i + KSEL * H] + part[i + 2 * KSEL * H] + part[i + 3 * KSEL * H];
    const float v = s + b[c];
    const int mf = *mflag;
    bool mv;
    if (mf == 2)      mv = ((const float*)mask)[i] != 0.f;
    else if (mf == 1) mv = ((const unsigned char*)mask)[i] != 0;
    else              mv = ((const int*)mask)[i] != 0;
    out[i] = mv ? bp[i] : v;
}

// ================= fallback (round-1 proven) path =================
__global__ __launch_bounds__(256) void k_fit_gemm(
    const float* __restrict__ pop, const float* __restrict__ w1,
    const float* __restrict__ bias1, const float* __restrict__ w2,
    float* __restrict__ xpart)
{
    __shared__ float As[16][128];
    __shared__ float Bs[16][128];
    const int nb   = blockIdx.x;
    const int row0 = blockIdx.y * 128;
    const int col0 = nb * 128;
    const int t  = threadIdx.x;
    const int tx = t & 15;
    const int ty = t >> 4;
    float acc[8][8];
#pragma unroll
    for (int i = 0; i < 8; ++i)
#pragma unroll
        for (int j = 0; j < 8; ++j) acc[i][j] = 0.f;
    const int lr = t >> 1;
    const int lk = (t & 1) * 8;
    const int bk = t >> 4;
    const int bc = (t & 15) * 8;
    for (int k0 = 0; k0 < H; k0 += 16) {
        const float4 a0 = *(const float4*)(pop + (size_t)(row0 + lr) * H + k0 + lk);
        const float4 a1 = *(const float4*)(pop + (size_t)(row0 + lr) * H + k0 + lk + 4);
        const float4 c0 = *(const float4*)(w1 + (size_t)(k0 + bk) * HH + col0 + bc);
        const float4 c1 = *(const float4*)(w1 + (size_t)(k0 + bk) * HH + col0 + bc + 4);
        __syncthreads();
        As[lk + 0][lr] = a0.x; As[lk + 1][lr] = a0.y; As[lk + 2][lr] = a0.z; As[lk + 3][lr] = a0.w;
        As[lk + 4][lr] = a1.x; As[lk + 5][lr] = a1.y; As[lk + 6][lr] = a1.z; As[lk + 7][lr] = a1.w;
        *(float4*)&Bs[bk][bc]     = c0;
        *(float4*)&Bs[bk][bc + 4] = c1;
        __syncthreads();
#pragma unroll
        for (int kk = 0; kk < 16; ++kk) {
            const float4 ra0 = *(const float4*)&As[kk][ty * 8];
            const float4 ra1 = *(const float4*)&As[kk][ty * 8 + 4];
            const float4 rb0 = *(const float4*)&Bs[kk][tx * 8];
            const float4 rb1 = *(const float4*)&Bs[kk][tx * 8 + 4];
            const float av[8] = {ra0.x, ra0.y, ra0.z, ra0.w, ra1.x, ra1.y, ra1.z, ra1.w};
            const float bv[8] = {rb0.x, rb0.y, rb0.z, rb0.w, rb1.x, rb1.y, rb1.z, rb1.w};
#pragma unroll
            for (int i = 0; i < 8; ++i)
#pragma unroll
                for (int j = 0; j < 8; ++j)
                    acc[i][j] = fmaf(av[i], bv[j], acc[i][j]);
        }
    }
    float part[8];
#pragma unroll
    for (int i = 0; i < 8; ++i) part[i] = 0.f;
#pragma unroll
    for (int j = 0; j < 8; ++j) {
        const int c = col0 + tx * 8 + j;
        const float bb = bias1[c];
        const float ww = w2[c];
#pragma unroll
        for (int i = 0; i < 8; ++i) {
            float hh = acc[i][j] + bb;
            hh = fmaxf(hh, 0.f);
            part[i] = fmaf(hh, ww, part[i]);
        }
    }
#pragma unroll
    for (int m = 1; m <= 8; m <<= 1)
#pragma unroll
        for (int i = 0; i < 8; ++i) part[i] += __shfl_xor(part[i], m);
    if (tx == 0) {
#pragma unroll
        for (int i = 0; i < 8; ++i)
            xpart[(size_t)(row0 + ty * 8 + i) * 8 + nb] = part[i];
    }
}

__global__ void k_fit_finish8(const float* __restrict__ xpart,
                              const float* __restrict__ b2, float* __restrict__ fit)
{
    const int i = blockIdx.x * 256 + threadIdx.x;
    if (i >= NPOP) return;
    float s = b2[0];
#pragma unroll
    for (int nb = 0; nb < 8; ++nb) s += xpart[(size_t)i * 8 + nb];
    fit[i] = 1.f / (1.f + expf(-s));
}

__global__ __launch_bounds__(256) void k_mut1(
    const float* __restrict__ pop, const int* __restrict__ best,
    const float* __restrict__ w, const float* __restrict__ b, float* __restrict__ mid)
{
    __shared__ float As[KSEL][32];
    __shared__ float Bs[32][64];
    __shared__ int sidx[KSEL];
    const int t = threadIdx.x;
    if (t < KSEL) sidx[t] = best[t];
    __syncthreads();
    const int col0 = blockIdx.x * 64;
    const int c  = t & 63;
    const int rg = t >> 6;
    float acc[13];
#pragma unroll
    for (int m = 0; m < 13; ++m) acc[m] = 0.f;
    for (int k0 = 0; k0 < H; k0 += 32) {
        __syncthreads();
        for (int e = t; e < KSEL * 32; e += 256) {
            const int r = e >> 5, kk = e & 31;
            As[r][kk] = pop[(size_t)sidx[r] * H + k0 + kk];
        }
        for (int e = t; e < 32 * 64; e += 256) {
            const int kk = e >> 6, cc = e & 63;
            Bs[kk][cc] = w[(size_t)(k0 + kk) * H + col0 + cc];
        }
        __syncthreads();
#pragma unroll
        for (int k4 = 0; k4 < 8; ++k4) {
            const float bv0 = Bs[k4 * 4 + 0][c];
            const float bv1 = Bs[k4 * 4 + 1][c];
            const float bv2 = Bs[k4 * 4 + 2][c];
            const float bv3 = Bs[k4 * 4 + 3][c];
#pragma unroll
            for (int m = 0; m < 13; ++m) {
                const int r = rg + m * 4;
                if (r < KSEL) {
                    const float4 av = *(const float4*)&As[r][k4 * 4];
                    acc[m] = fmaf(av.x, bv0, acc[m]);
                    acc[m] = fmaf(av.y, bv1, acc[m]);
                    acc[m] = fmaf(av.z, bv2, acc[m]);
                    acc[m] = fmaf(av.w, bv3, acc[m]);
                }
            }
        }
    }
#pragma unroll
    for (int m = 0; m < 13; ++m) {
        const int r = rg + m * 4;
        if (r < KSEL) {
            const int col = col0 + c;
            const float v = acc[m] + b[col];
            mid[(size_t)r * H + col] = 0.5f * v * (1.f + erff(v * 0.70710678118654752f));
        }
    }
}

__global__ __launch_bounds__(256) void k_mut2(
    const float* __restrict__ mid, const float* __restrict__ w,
    const float* __restrict__ b, const float* __restrict__ pop,
    const int* __restrict__ best, const void* __restrict__ mask,
    const int* __restrict__ mflag, float* __restrict__ out)
{
    __shared__ float As[KSEL][32];
    __shared__ float Bs[32][64];
    __shared__ int sidx[KSEL];
    const int t = threadIdx.x;
    if (t < KSEL) sidx[t] = best[t];
    __syncthreads();
    const int col0 = blockIdx.x * 64;
    const int c  = t & 63;
    const int rg = t >> 6;
    const int mf = *mflag;
    float acc[13];
#pragma unroll
    for (int m = 0; m < 13; ++m) acc[m] = 0.f;
    for (int k0 = 0; k0 < H; k0 += 32) {
        __syncthreads();
        for (int e = t; e < KSEL * 32; e += 256) {
            const int r = e >> 5, kk = e & 31;
            As[r][kk] = mid[(size_t)r * H + k0 + kk];
        }
        for (int e = t; e < 32 * 64; e += 256) {
            const int kk = e >> 6, cc = e & 63;
            Bs[kk][cc] = w[(size_t)(k0 + kk) * H + col0 + cc];
        }
        __syncthreads();
#pragma unroll
        for (int k4 = 0; k4 < 8; ++k4) {
            const float bv0 = Bs[k4 * 4 + 0][c];
            const float bv1 = Bs[k4 * 4 + 1][c];
            const float bv2 = Bs[k4 * 4 + 2][c];
            const float bv3 = Bs[k4 * 4 + 3][c];
#pragma unroll
            for (int m = 0; m < 13; ++m) {
                const int r = rg + m * 4;
                if (r < KSEL) {
                    const float4 av = *(const float4*)&As[r][k4 * 4];
                    acc[m] = fmaf(av.x, bv0, acc[m]);
                    acc[m] = fmaf(av.y, bv1, acc[m]);
                    acc[m] = fmaf(av.z, bv2, acc[m]);
                    acc[m] = fmaf(av.w, bv3, acc[m]);
                }
            }
        }
    }
#pragma unroll
    for (int m = 0; m < 13; ++m) {
        const int r = rg + m * 4;
        if (r < KSEL) {
            const int col = col0 + c;
            const size_t mi = (size_t)r * H + col;
            const float v = acc[m] + b[col];
            bool mv;
            if (mf == 2)      mv = ((const float*)mask)[mi] != 0.f;
            else if (mf == 1) mv = ((const unsigned char*)mask)[mi] != 0;
            else              mv = ((const int*)mask)[mi] != 0;
            out[mi] = mv ? pop[(size_t)sidx[r] * H + col] : v;
        }
    }
}

// ================= launcher =================
extern "C" void kernel_launch(void* const* d_in, const int* in_sizes, int n_in,
                              void* d_out, int out_size, void* d_ws, size_t ws_size,
                              hipStream_t stream) {
    const float* pop = (const float*)d_in[0];
    const float* sw1 = (const float*)d_in[1];
    const float* sb1 = (const float*)d_in[2];
    const float* sw2 = (const float*)d_in[3];
    const float* sb2 = (const float*)d_in[4];
    const float* mw1 = (const float*)d_in[5];
    const float* mb1 = (const float*)d_in[6];
    const float* mw2 = (const float*)d_in[7];
    const float* mb2 = (const float*)d_in[8];
    const void*  mask = d_in[9];

    float* out_off = (float*)d_out;
    float* out_fit = (float*)d_out + (size_t)KSEL * H;

    char* ws = (char*)d_ws;

    // fast-path ws layout (bytes)
    const size_t W1TH_OFF = 0;
    const size_t W1TL_OFF = 4194304;
    const size_t XPART_OFF = 8388608;
    const size_t PMID_OFF = 12582912;          // 4*50*2048 f32 = 1,638,400
    const size_t POUT_OFF = 14221312;
    const size_t MID_OFF  = 15859712;          // 409,600
    const size_t BP_OFF   = 16269312;          // 409,600
    const size_t BEST_OFF = 16678912;
    const size_t MFLAG_OFF = 16679168;
    const size_t NEED = 16679424;

    if (ws_size >= NEED) {
        unsigned short* w1th = (unsigned short*)(ws + W1TH_OFF);
        unsigned short* w1tl = (unsigned short*)(ws + W1TL_OFF);
        float* xpart = (float*)(ws + XPART_OFF);
        float* pmid  = (float*)(ws + PMID_OFF);
        float* pout  = (float*)(ws + POUT_OFF);
        float* mid   = (float*)(ws + MID_OFF);
        float* bp    = (float*)(ws + BP_OFF);
        int*   best  = (int*)(ws + BEST_OFF);
        int*   mflag = (int*)(ws + MFLAG_OFF);

        hipLaunchKernelGGL(k_maskdetect, dim3(1), dim3(256), 0, stream,
                           (const unsigned int*)mask, mflag);
        hipLaunchKernelGGL(k_w1split, dim3(16, 32), dim3(256), 0, stream, sw1, w1th, w1tl);
        hipLaunchKernelGGL(k_fit_mfma, dim3(8, 512), dim3(256), 0, stream,
                           pop, w1th, w1tl, sb1, sw2, xpart);
        hipLaunchKernelGGL(k_fit_finish16, dim3(NPOP / 256), dim3(256), 0, stream,
                           xpart, sb2, out_fit);
        hipLaunchKernelGGL(k_topk2, dim3(1), dim3(1024), 0, stream, out_fit, best);
        hipLaunchKernelGGL(k_gather, dim3(KSEL * H / 256), dim3(256), 0, stream, pop, best, bp);
        hipLaunchKernelGGL(k_mutp, dim3(32, 4), dim3(256), 0, stream, bp, mw1, pmid);
        hipLaunchKernelGGL(k_mut1c, dim3(KSEL * H / 256), dim3(256), 0, stream, pmid, mb1, mid);
        hipLaunchKernelGGL(k_mutp, dim3(32, 4), dim3(256), 0, stream, mid, mw2, pout);
        hipLaunchKernelGGL(k_mut2c, dim3(KSEL * H / 256), dim3(256), 0, stream,
                           pout, mb2, bp, mask, mflag, out_off);
    } else {
        // fallback: round-1 proven path
        float* xpart = (float*)ws;                                   // 2 MB
        int*   best  = (int*)(ws + (size_t)NPOP * 8 * 4);
        int*   mflag = (int*)(ws + (size_t)NPOP * 8 * 4 + 256);
        float* mid   = (float*)(ws + (size_t)NPOP * 8 * 4 + 512);

        hipLaunchKernelGGL(k_maskdetect, dim3(1), dim3(256), 0, stream,
                           (const unsigned int*)mask, mflag);
        hipLaunchKernelGGL(k_fit_gemm, dim3(8, 512), dim3(256), 0, stream,
                           pop, sw1, sb1, sw2, xpart);
        hipLaunchKernelGGL(k_fit_finish8, dim3(NPOP / 256), dim3(256), 0, stream,
                           xpart, sb2, out_fit);
        hipLaunchKernelGGL(k_topk2, dim3(1), dim3(1024), 0, stream, out_fit, best);
        hipLaunchKernelGGL(k_mut1, dim3(H / 64), dim3(256), 0, stream,
                           pop, best, mw1, mb1, mid);
        hipLaunchKernelGGL(k_mut2, dim3(H / 64), dim3(256), 0, stream,
                           mid, mw2, mb2, pop, best, mask, mflag, out_off);
    }
}

// Round 3
// 905.198 us; speedup vs baseline: 5.5213x; 1.7983x over previous
//
#include <hip/hip_runtime.h>
#include <math.h>

#define NPOP 65536
#define H    2048
#define HH   1024
#define KSEL 50

using bf16x8 = __attribute__((ext_vector_type(8))) short;
using f32x4  = __attribute__((ext_vector_type(4))) float;

__device__ __forceinline__ unsigned short f2bf(float x) {
    unsigned u = __float_as_uint(x);
    return (unsigned short)((u + 0x7FFFu + ((u >> 16) & 1u)) >> 16);
}

// ---------------- mask dtype detection ----------------
__global__ void k_maskdetect(const unsigned int* __restrict__ m, int* __restrict__ flag) {
    __shared__ int sfloat, sbyte;
    if (threadIdx.x == 0) { sfloat = 0; sbyte = 0; }
    __syncthreads();
    for (int i = threadIdx.x; i < 25600; i += 256) {
        unsigned int v = m[i];
        if (v == 0x3F800000u) sfloat = 1;
        else if (v & 0xFFFFFF00u) sbyte = 1;
    }
    __syncthreads();
    if (threadIdx.x == 0) *flag = sfloat ? 2 : (sbyte ? 1 : 0);
}

// ---------------- W1 transpose + bf16 hi/lo split, chunk-PERMUTED store ----------------
// w1 [2048][1024] f32 -> w1t_hi/lo [1024][2048] bf16 bits.
// Within each 64-k tile, 8-elem chunk c is stored at slot c^(row&7) so that a
// LINEAR global_load_lds lands it at the XOR-swizzled LDS slot (G21 pattern).
__global__ __launch_bounds__(256) void k_w1split(
    const float* __restrict__ w1,
    unsigned short* __restrict__ th, unsigned short* __restrict__ tl)
{
    __shared__ float tile[64][65];
    const int t = threadIdx.x;
    const int n0 = blockIdx.x * 64;
    const int k0 = blockIdx.y * 64;
#pragma unroll
    for (int p = 0; p < 4; ++p) {
        const int kr = (t >> 4) + p * 16;
        const int nc = (t & 15) * 4;
        const float4 v = *(const float4*)&w1[(size_t)(k0 + kr) * HH + n0 + nc];
        tile[kr][nc] = v.x; tile[kr][nc + 1] = v.y; tile[kr][nc + 2] = v.z; tile[kr][nc + 3] = v.w;
    }
    __syncthreads();
#pragma unroll
    for (int p = 0; p < 4; ++p) {
        const int nr = (t >> 4) + p * 16;
        const int kc = (t & 15) * 4;
        unsigned hh[4], ll[4];
#pragma unroll
        for (int e = 0; e < 4; ++e) {
            const float x = tile[kc + e][nr];
            const unsigned short hb = f2bf(x);
            const float hf = __uint_as_float((unsigned)hb << 16);
            hh[e] = hb;
            ll[e] = f2bf(x - hf);
        }
        uint2 ph, pl;
        ph.x = hh[0] | (hh[1] << 16); ph.y = hh[2] | (hh[3] << 16);
        pl.x = ll[0] | (ll[1] << 16); pl.y = ll[2] | (ll[3] << 16);
        // permuted k position within the 64-tile
        const int ks = (((kc >> 3) ^ (nr & 7)) << 3) | (kc & 7);
        *(uint2*)&th[(size_t)(n0 + nr) * H + k0 + ks] = ph;
        *(uint2*)&tl[(size_t)(n0 + nr) * H + k0 + ks] = pl;
    }
}

// ---------------- fitness GEMM via 3-term bf16-split MFMA ----------------
// 1-D grid 4096 (chunked XCD swizzle), 256 threads (4 waves, 2m x 2n).
// Block tile 128 rows x 128 cols, BK=64. A: truncation hi/lo split in regs.
// B: global_load_lds width-16 from pre-permuted w1t. Fused relu + w2 epilogue.
__global__ __launch_bounds__(256) void k_fit_mfma(
    const float* __restrict__ pop,
    const unsigned short* __restrict__ w1h, const unsigned short* __restrict__ w1l,
    const float* __restrict__ bias1, const float* __restrict__ w2,
    float* __restrict__ xpart)
{
    __shared__ unsigned short Ah[128 * 64];
    __shared__ unsigned short Al[128 * 64];
    __shared__ unsigned short Bh[128 * 64];
    __shared__ unsigned short Bl[128 * 64];
    const int t = threadIdx.x;
    const int lane = t & 63;
    const int wid = t >> 6;
    const int wm = wid >> 1, wn = wid & 1;

    // chunked XCD swizzle: xcd = bid%8 gets contiguous 512-block range
    const int lin = (blockIdx.x & 7) * 512 + (blockIdx.x >> 3);
    const int row0 = (lin >> 3) * 128;
    const int nb = lin & 7;
    const int col0 = nb * 128;

    f32x4 acc[4][4];
#pragma unroll
    for (int i = 0; i < 4; ++i)
#pragma unroll
        for (int j = 0; j < 4; ++j) { f32x4 z = {0.f, 0.f, 0.f, 0.f}; acc[i][j] = z; }

    // LDS fragment read offsets (elements) for kk=0; kk=1 is XOR 32.
    int aoff[4], boff[4];
#pragma unroll
    for (int i = 0; i < 4; ++i) {
        const int ra = wm * 64 + i * 16 + (lane & 15);
        aoff[i] = ra * 64 + (((lane >> 4) ^ (ra & 7)) * 8);
        const int rb = wn * 64 + i * 16 + (lane & 15);
        boff[i] = rb * 64 + (((lane >> 4) ^ (rb & 7)) * 8);
    }
    // A staging: thread t covers rows (t>>3)+32q, 8-elem chunk (t&7), swizzled
    int woff[4];
#pragma unroll
    for (int q = 0; q < 4; ++q) {
        const int r = (t >> 3) + 32 * q;
        woff[q] = r * 64 + (((t & 7) ^ (r & 7)) * 8);
    }
    const float* asrc = pop + (size_t)(row0 + (t >> 3)) * H + (t & 7) * 8;
    // B staging: wave wid covers rows wid*32 + q*8 + (lane>>3), linear LDS dest
    const unsigned short* bh_src = w1h + (size_t)(col0 + wid * 32 + (lane >> 3)) * H + (lane & 7) * 8;
    const unsigned short* bl_src = w1l + (size_t)(col0 + wid * 32 + (lane >> 3)) * H + (lane & 7) * 8;

    for (int k0 = 0; k0 < H; k0 += 64) {
        __syncthreads();   // previous iter's LDS reads complete
        // B: async direct-to-LDS (linear dest == pre-permuted source)
#pragma unroll
        for (int q = 0; q < 4; ++q) {
            __builtin_amdgcn_global_load_lds(
                (const __attribute__((address_space(1))) void*)(bh_src + (size_t)q * 8 * H + k0),
                (__attribute__((address_space(3))) void*)&Bh[(wid * 32 + q * 8) * 64],
                16, 0, 0);
            __builtin_amdgcn_global_load_lds(
                (const __attribute__((address_space(1))) void*)(bl_src + (size_t)q * 8 * H + k0),
                (__attribute__((address_space(3))) void*)&Bl[(wid * 32 + q * 8) * 64],
                16, 0, 0);
        }
        // A: load fp32, truncation hi/lo split (4 VALU ops/elem), ds_write
#pragma unroll
        for (int q = 0; q < 4; ++q) {
            const float* s = asrc + (size_t)(32 * q) * H + k0;
            const float4 a0 = *(const float4*)s;
            const float4 a1 = *(const float4*)(s + 4);
            const float xs[8] = {a0.x, a0.y, a0.z, a0.w, a1.x, a1.y, a1.z, a1.w};
            bf16x8 hv, lv;
#pragma unroll
            for (int e = 0; e < 8; ++e) {
                const unsigned u = __float_as_uint(xs[e]);
                hv[e] = (short)(u >> 16);
                const float hf = __uint_as_float(u & 0xFFFF0000u);
                lv[e] = (short)(__float_as_uint(xs[e] - hf) >> 16);
            }
            *(bf16x8*)&Ah[woff[q]] = hv;
            *(bf16x8*)&Al[woff[q]] = lv;
        }
        __syncthreads();
#pragma unroll
        for (int kk = 0; kk < 2; ++kk) {
            const int x = kk * 32;
            bf16x8 ah[4], al[4], bh[4], bl[4];
#pragma unroll
            for (int i = 0; i < 4; ++i) {
                ah[i] = *(const bf16x8*)&Ah[aoff[i] ^ x];
                al[i] = *(const bf16x8*)&Al[aoff[i] ^ x];
                bh[i] = *(const bf16x8*)&Bh[boff[i] ^ x];
                bl[i] = *(const bf16x8*)&Bl[boff[i] ^ x];
            }
#pragma unroll
            for (int i = 0; i < 4; ++i)
#pragma unroll
                for (int j = 0; j < 4; ++j) {
                    acc[i][j] = __builtin_amdgcn_mfma_f32_16x16x32_bf16(ah[i], bh[j], acc[i][j], 0, 0, 0);
                    acc[i][j] = __builtin_amdgcn_mfma_f32_16x16x32_bf16(ah[i], bl[j], acc[i][j], 0, 0, 0);
                    acc[i][j] = __builtin_amdgcn_mfma_f32_16x16x32_bf16(al[i], bh[j], acc[i][j], 0, 0, 0);
                }
        }
    }

    // epilogue: relu + w2 dot, reduce over 16 cols x 4 j-frags
    float part[4][4];
#pragma unroll
    for (int i = 0; i < 4; ++i)
#pragma unroll
        for (int rg = 0; rg < 4; ++rg) part[i][rg] = 0.f;
#pragma unroll
    for (int j = 0; j < 4; ++j) {
        const int col = col0 + wn * 64 + j * 16 + (lane & 15);
        const float b1c = bias1[col];
        const float w2c = w2[col];
#pragma unroll
        for (int i = 0; i < 4; ++i)
#pragma unroll
            for (int rg = 0; rg < 4; ++rg) {
                float hval = acc[i][j][rg] + b1c;
                hval = fmaxf(hval, 0.f);
                part[i][rg] = fmaf(hval, w2c, part[i][rg]);
            }
    }
#pragma unroll
    for (int m = 1; m <= 8; m <<= 1)
#pragma unroll
        for (int i = 0; i < 4; ++i)
#pragma unroll
            for (int rg = 0; rg < 4; ++rg)
                part[i][rg] += __shfl_xor(part[i][rg], m);
    if ((lane & 15) == 0) {
#pragma unroll
        for (int i = 0; i < 4; ++i)
#pragma unroll
            for (int rg = 0; rg < 4; ++rg) {
                const int row = row0 + wm * 64 + i * 16 + (lane >> 4) * 4 + rg;
                xpart[(size_t)row * 16 + nb * 2 + wn] = part[i][rg];
            }
    }
}

__global__ void k_fit_finish16(const float* __restrict__ xpart,
                               const float* __restrict__ b2, float* __restrict__ fit)
{
    const int i = blockIdx.x * 256 + threadIdx.x;
    if (i >= NPOP) return;
    float s = b2[0];
#pragma unroll
    for (int c = 0; c < 16; ++c) s += xpart[(size_t)i * 16 + c];
    fit[i] = 1.f / (1.f + expf(-s));
}

// ---------------- top-50: cached slice maxima, wave-parallel rescan ----------------
__global__ __launch_bounds__(1024) void k_topk3(const float* __restrict__ fit,
                                                int* __restrict__ best)
{
    __shared__ unsigned long long skey[1024];
    __shared__ unsigned long long wred[16];
    __shared__ unsigned int taken[NPOP / 32];
    __shared__ int brd;
    const int t = threadIdx.x;
    for (int i = t; i < NPOP / 32; i += 1024) taken[i] = 0u;
    unsigned long long k = 0ull;
#pragma unroll 4
    for (int i = 0; i < 64; ++i) {
        const int idx = t + (i << 10);
        const unsigned fv = __float_as_uint(fit[idx]);
        const unsigned long long key = ((unsigned long long)fv << 32) | (unsigned)(~(unsigned)idx);
        if (key > k) k = key;
    }
    skey[t] = k;
    __syncthreads();
    for (int r = 0; r < KSEL; ++r) {
        unsigned long long v = skey[t];
#pragma unroll
        for (int m = 32; m >= 1; m >>= 1) {
            const unsigned long long o = __shfl_xor(v, m);
            if (o > v) v = o;
        }
        if ((t & 63) == 0) wred[t >> 6] = v;
        __syncthreads();
        if (t == 0) {
            unsigned long long b = wred[0];
#pragma unroll
            for (int w = 1; w < 16; ++w) if (wred[w] > b) b = wred[w];
            const int idx = (int)(~(unsigned)(b & 0xFFFFFFFFull));
            best[r] = idx;
            taken[idx >> 5] |= (1u << (idx & 31));
            brd = idx;
        }
        __syncthreads();
        if (r + 1 < KSEL) {
            const int s = brd & 1023;
            if (t < 64) {   // wave 0 recomputes the winning slice's max
                const int e = s + (t << 10);
                unsigned long long k2 = 0ull;
                if (!(taken[e >> 5] & (1u << (e & 31)))) {
                    const unsigned fv = __float_as_uint(fit[e]);
                    k2 = ((unsigned long long)fv << 32) | (unsigned)(~(unsigned)e);
                }
#pragma unroll
                for (int m = 32; m >= 1; m >>= 1) {
                    const unsigned long long o = __shfl_xor(k2, m);
                    if (o > k2) k2 = o;
                }
                if (t == 0) skey[s] = k2;
            }
            __syncthreads();
        }
    }
}

// ---------------- gather best rows ----------------
__global__ void k_gather(const float* __restrict__ pop, const int* __restrict__ best,
                         float* __restrict__ bp)
{
    const int i = blockIdx.x * 256 + threadIdx.x;
    if (i >= KSEL * H) return;
    const int r = i >> 11, c = i & 2047;
    bp[i] = pop[(size_t)best[r] * H + c];
}

// ---------------- mutation partial GEMM (split-K x8) ----------------
// grid (32 colblocks, 8 kchunks), 256 threads. part[ks][50][2048], no bias.
__global__ __launch_bounds__(256) void k_mutp(
    const float* __restrict__ A, const float* __restrict__ W, float* __restrict__ part)
{
    __shared__ float As[KSEL][32];
    __shared__ float Bs[32][64];
    const int t = threadIdx.x;
    const int col0 = blockIdx.x * 64;
    const int kbeg = blockIdx.y * 256;
    const int c = t & 63;
    const int rg = t >> 6;
    float acc[13];
#pragma unroll
    for (int m = 0; m < 13; ++m) acc[m] = 0.f;

    for (int k0 = kbeg; k0 < kbeg + 256; k0 += 32) {
        __syncthreads();
        for (int e = t; e < KSEL * 8; e += 256) {
            const int r = e >> 3, kc = (e & 7) << 2;
            *(float4*)&As[r][kc] = *(const float4*)&A[(size_t)r * H + k0 + kc];
        }
        for (int e = t; e < 32 * 16; e += 256) {
            const int kk = e >> 4, cc = (e & 15) << 2;
            *(float4*)&Bs[kk][cc] = *(const float4*)&W[(size_t)(k0 + kk) * H + col0 + cc];
        }
        __syncthreads();
#pragma unroll
        for (int k4 = 0; k4 < 8; ++k4) {
            const float bv0 = Bs[k4 * 4 + 0][c];
            const float bv1 = Bs[k4 * 4 + 1][c];
            const float bv2 = Bs[k4 * 4 + 2][c];
            const float bv3 = Bs[k4 * 4 + 3][c];
#pragma unroll
            for (int m = 0; m < 13; ++m) {
                const int r = rg + m * 4;
                if (r < KSEL) {
                    const float4 av = *(const float4*)&As[r][k4 * 4];
                    acc[m] = fmaf(av.x, bv0, acc[m]);
                    acc[m] = fmaf(av.y, bv1, acc[m]);
                    acc[m] = fmaf(av.z, bv2, acc[m]);
                    acc[m] = fmaf(av.w, bv3, acc[m]);
                }
            }
        }
    }
#pragma unroll
    for (int m = 0; m < 13; ++m) {
        const int r = rg + m * 4;
        if (r < KSEL)
            part[((size_t)blockIdx.y * KSEL + r) * H + col0 + c] = acc[m];
    }
}

__global__ void k_mut1c(const float* __restrict__ part, const float* __restrict__ b,
                        float* __restrict__ mid)
{
    const int i = blockIdx.x * 256 + threadIdx.x;
    if (i >= KSEL * H) return;
    const int c = i & 2047;
    float s = 0.f;
#pragma unroll
    for (int p = 0; p < 8; ++p) s += part[i + (size_t)p * KSEL * H];
    const float v = s + b[c];
    mid[i] = 0.5f * v * (1.f + erff(v * 0.70710678118654752f));
}

__global__ void k_mut2c(const float* __restrict__ part, const float* __restrict__ b,
                        const float* __restrict__ bp, const void* __restrict__ mask,
                        const int* __restrict__ mflag, float* __restrict__ out)
{
    const int i = blockIdx.x * 256 + threadIdx.x;
    if (i >= KSEL * H) return;
    const int c = i & 2047;
    float s = 0.f;
#pragma unroll
    for (int p = 0; p < 8; ++p) s += part[i + (size_t)p * KSEL * H];
    const float v = s + b[c];
    const int mf = *mflag;
    bool mv;
    if (mf == 2)      mv = ((const float*)mask)[i] != 0.f;
    else if (mf == 1) mv = ((const unsigned char*)mask)[i] != 0;
    else              mv = ((const int*)mask)[i] != 0;
    out[i] = mv ? bp[i] : v;
}

// ================= fallback (round-1 proven) path =================
__global__ __launch_bounds__(256) void k_fit_gemm(
    const float* __restrict__ pop, const float* __restrict__ w1,
    const float* __restrict__ bias1, const float* __restrict__ w2,
    float* __restrict__ xpart)
{
    __shared__ float As[16][128];
    __shared__ float Bs[16][128];
    const int nb   = blockIdx.x;
    const int row0 = blockIdx.y * 128;
    const int col0 = nb * 128;
    const int t  = threadIdx.x;
    const int tx = t & 15;
    const int ty = t >> 4;
    float acc[8][8];
#pragma unroll
    for (int i = 0; i < 8; ++i)
#pragma unroll
        for (int j = 0; j < 8; ++j) acc[i][j] = 0.f;
    const int lr = t >> 1;
    const int lk = (t & 1) * 8;
    const int bk = t >> 4;
    const int bc = (t & 15) * 8;
    for (int k0 = 0; k0 < H; k0 += 16) {
        const float4 a0 = *(const float4*)(pop + (size_t)(row0 + lr) * H + k0 + lk);
        const float4 a1 = *(const float4*)(pop + (size_t)(row0 + lr) * H + k0 + lk + 4);
        const float4 c0 = *(const float4*)(w1 + (size_t)(k0 + bk) * HH + col0 + bc);
        const float4 c1 = *(const float4*)(w1 + (size_t)(k0 + bk) * HH + col0 + bc + 4);
        __syncthreads();
        As[lk + 0][lr] = a0.x; As[lk + 1][lr] = a0.y; As[lk + 2][lr] = a0.z; As[lk + 3][lr] = a0.w;
        As[lk + 4][lr] = a1.x; As[lk + 5][lr] = a1.y; As[lk + 6][lr] = a1.z; As[lk + 7][lr] = a1.w;
        *(float4*)&Bs[bk][bc]     = c0;
        *(float4*)&Bs[bk][bc + 4] = c1;
        __syncthreads();
#pragma unroll
        for (int kk = 0; kk < 16; ++kk) {
            const float4 ra0 = *(const float4*)&As[kk][ty * 8];
            const float4 ra1 = *(const float4*)&As[kk][ty * 8 + 4];
            const float4 rb0 = *(const float4*)&Bs[kk][tx * 8];
            const float4 rb1 = *(const float4*)&Bs[kk][tx * 8 + 4];
            const float av[8] = {ra0.x, ra0.y, ra0.z, ra0.w, ra1.x, ra1.y, ra1.z, ra1.w};
            const float bv[8] = {rb0.x, rb0.y, rb0.z, rb0.w, rb1.x, rb1.y, rb1.z, rb1.w};
#pragma unroll
            for (int i = 0; i < 8; ++i)
#pragma unroll
                for (int j = 0; j < 8; ++j)
                    acc[i][j] = fmaf(av[i], bv[j], acc[i][j]);
        }
    }
    float part[8];
#pragma unroll
    for (int i = 0; i < 8; ++i) part[i] = 0.f;
#pragma unroll
    for (int j = 0; j < 8; ++j) {
        const int c = col0 + tx * 8 + j;
        const float bb = bias1[c];
        const float ww = w2[c];
#pragma unroll
        for (int i = 0; i < 8; ++i) {
            float hh = acc[i][j] + bb;
            hh = fmaxf(hh, 0.f);
            part[i] = fmaf(hh, ww, part[i]);
        }
    }
#pragma unroll
    for (int m = 1; m <= 8; m <<= 1)
#pragma unroll
        for (int i = 0; i < 8; ++i) part[i] += __shfl_xor(part[i], m);
    if (tx == 0) {
#pragma unroll
        for (int i = 0; i < 8; ++i)
            xpart[(size_t)(row0 + ty * 8 + i) * 8 + nb] = part[i];
    }
}

__global__ void k_fit_finish8(const float* __restrict__ xpart,
                              const float* __restrict__ b2, float* __restrict__ fit)
{
    const int i = blockIdx.x * 256 + threadIdx.x;
    if (i >= NPOP) return;
    float s = b2[0];
#pragma unroll
    for (int nb = 0; nb < 8; ++nb) s += xpart[(size_t)i * 8 + nb];
    fit[i] = 1.f / (1.f + expf(-s));
}

__global__ __launch_bounds__(256) void k_mut1(
    const float* __restrict__ pop, const int* __restrict__ best,
    const float* __restrict__ w, const float* __restrict__ b, float* __restrict__ mid)
{
    __shared__ float As[KSEL][32];
    __shared__ float Bs[32][64];
    __shared__ int sidx[KSEL];
    const int t = threadIdx.x;
    if (t < KSEL) sidx[t] = best[t];
    __syncthreads();
    const int col0 = blockIdx.x * 64;
    const int c  = t & 63;
    const int rg = t >> 6;
    float acc[13];
#pragma unroll
    for (int m = 0; m < 13; ++m) acc[m] = 0.f;
    for (int k0 = 0; k0 < H; k0 += 32) {
        __syncthreads();
        for (int e = t; e < KSEL * 32; e += 256) {
            const int r = e >> 5, kk = e & 31;
            As[r][kk] = pop[(size_t)sidx[r] * H + k0 + kk];
        }
        for (int e = t; e < 32 * 64; e += 256) {
            const int kk = e >> 6, cc = e & 63;
            Bs[kk][cc] = w[(size_t)(k0 + kk) * H + col0 + cc];
        }
        __syncthreads();
#pragma unroll
        for (int k4 = 0; k4 < 8; ++k4) {
            const float bv0 = Bs[k4 * 4 + 0][c];
            const float bv1 = Bs[k4 * 4 + 1][c];
            const float bv2 = Bs[k4 * 4 + 2][c];
            const float bv3 = Bs[k4 * 4 + 3][c];
#pragma unroll
            for (int m = 0; m < 13; ++m) {
                const int r = rg + m * 4;
                if (r < KSEL) {
                    const float4 av = *(const float4*)&As[r][k4 * 4];
                    acc[m] = fmaf(av.x, bv0, acc[m]);
                    acc[m] = fmaf(av.y, bv1, acc[m]);
                    acc[m] = fmaf(av.z, bv2, acc[m]);
                    acc[m] = fmaf(av.w, bv3, acc[m]);
                }
            }
        }
    }
#pragma unroll
    for (int m = 0; m < 13; ++m) {
        const int r = rg + m * 4;
        if (r < KSEL) {
            const int col = col0 + c;
            const float v = acc[m] + b[col];
            mid[(size_t)r * H + col] = 0.5f * v * (1.f + erff(v * 0.70710678118654752f));
        }
    }
}

__global__ __launch_bounds__(256) void k_mut2(
    const float* __restrict__ mid, const float* __restrict__ w,
    const float* __restrict__ b, const float* __restrict__ pop,
    const int* __restrict__ best, const void* __restrict__ mask,
    const int* __restrict__ mflag, float* __restrict__ out)
{
    __shared__ float As[KSEL][32];
    __shared__ float Bs[32][64];
    __shared__ int sidx[KSEL];
    const int t = threadIdx.x;
    if (t < KSEL) sidx[t] = best[t];
    __syncthreads();
    const int col0 = blockIdx.x * 64;
    const int c  = t & 63;
    const int rg = t >> 6;
    const int mf = *mflag;
    float acc[13];
#pragma unroll
    for (int m = 0; m < 13; ++m) acc[m] = 0.f;
    for (int k0 = 0; k0 < H; k0 += 32) {
        __syncthreads();
        for (int e = t; e < KSEL * 32; e += 256) {
            const int r = e >> 5, kk = e & 31;
            As[r][kk] = mid[(size_t)r * H + k0 + kk];
        }
        for (int e = t; e < 32 * 64; e += 256) {
            const int kk = e >> 6, cc = e & 63;
            Bs[kk][cc] = w[(size_t)(k0 + kk) * H + col0 + cc];
        }
        __syncthreads();
#pragma unroll
        for (int k4 = 0; k4 < 8; ++k4) {
            const float bv0 = Bs[k4 * 4 + 0][c];
            const float bv1 = Bs[k4 * 4 + 1][c];
            const float bv2 = Bs[k4 * 4 + 2][c];
            const float bv3 = Bs[k4 * 4 + 3][c];
#pragma unroll
            for (int m = 0; m < 13; ++m) {
                const int r = rg + m * 4;
                if (r < KSEL) {
                    const float4 av = *(const float4*)&As[r][k4 * 4];
                    acc[m] = fmaf(av.x, bv0, acc[m]);
                    acc[m] = fmaf(av.y, bv1, acc[m]);
                    acc[m] = fmaf(av.z, bv2, acc[m]);
                    acc[m] = fmaf(av.w, bv3, acc[m]);
                }
            }
        }
    }
#pragma unroll
    for (int m = 0; m < 13; ++m) {
        const int r = rg + m * 4;
        if (r < KSEL) {
            const int col = col0 + c;
            const size_t mi = (size_t)r * H + col;
            const float v = acc[m] + b[col];
            bool mv;
            if (mf == 2)      mv = ((const float*)mask)[mi] != 0.f;
            else if (mf == 1) mv = ((const unsigned char*)mask)[mi] != 0;
            else              mv = ((const int*)mask)[mi] != 0;
            out[mi] = mv ? pop[(size_t)sidx[r] * H + col] : v;
        }
    }
}

// ================= launcher =================
extern "C" void kernel_launch(void* const* d_in, const int* in_sizes, int n_in,
                              void* d_out, int out_size, void* d_ws, size_t ws_size,
                              hipStream_t stream) {
    const float* pop = (const float*)d_in[0];
    const float* sw1 = (const float*)d_in[1];
    const float* sb1 = (const float*)d_in[2];
    const float* sw2 = (const float*)d_in[3];
    const float* sb2 = (const float*)d_in[4];
    const float* mw1 = (const float*)d_in[5];
    const float* mb1 = (const float*)d_in[6];
    const float* mw2 = (const float*)d_in[7];
    const float* mb2 = (const float*)d_in[8];
    const void*  mask = d_in[9];

    float* out_off = (float*)d_out;
    float* out_fit = (float*)d_out + (size_t)KSEL * H;

    char* ws = (char*)d_ws;

    // fast-path ws layout (bytes) — NEED identical to round-2 proven value
    const size_t W1TH_OFF  = 0;          // 4,194,304
    const size_t W1TL_OFF  = 4194304;    // 4,194,304
    const size_t XPART_OFF = 8388608;    // 4,194,304
    const size_t PPART_OFF = 12582912;   // 8*50*2048*4 = 3,276,800 (shared by both layers)
    const size_t MID_OFF   = 15859712;   // 409,600
    const size_t BP_OFF    = 16269312;   // 409,600
    const size_t BEST_OFF  = 16678912;   // 256
    const size_t MFLAG_OFF = 16679168;   // 256
    const size_t NEED      = 16679424;

    if (ws_size >= NEED) {
        unsigned short* w1th = (unsigned short*)(ws + W1TH_OFF);
        unsigned short* w1tl = (unsigned short*)(ws + W1TL_OFF);
        float* xpart = (float*)(ws + XPART_OFF);
        float* ppart = (float*)(ws + PPART_OFF);
        float* mid   = (float*)(ws + MID_OFF);
        float* bp    = (float*)(ws + BP_OFF);
        int*   best  = (int*)(ws + BEST_OFF);
        int*   mflag = (int*)(ws + MFLAG_OFF);

        hipLaunchKernelGGL(k_maskdetect, dim3(1), dim3(256), 0, stream,
                           (const unsigned int*)mask, mflag);
        hipLaunchKernelGGL(k_w1split, dim3(16, 32), dim3(256), 0, stream, sw1, w1th, w1tl);
        hipLaunchKernelGGL(k_fit_mfma, dim3(4096), dim3(256), 0, stream,
                           pop, w1th, w1tl, sb1, sw2, xpart);
        hipLaunchKernelGGL(k_fit_finish16, dim3(NPOP / 256), dim3(256), 0, stream,
                           xpart, sb2, out_fit);
        hipLaunchKernelGGL(k_topk3, dim3(1), dim3(1024), 0, stream, out_fit, best);
        hipLaunchKernelGGL(k_gather, dim3(KSEL * H / 256), dim3(256), 0, stream, pop, best, bp);
        hipLaunchKernelGGL(k_mutp, dim3(32, 8), dim3(256), 0, stream, bp, mw1, ppart);
        hipLaunchKernelGGL(k_mut1c, dim3(KSEL * H / 256), dim3(256), 0, stream, ppart, mb1, mid);
        hipLaunchKernelGGL(k_mutp, dim3(32, 8), dim3(256), 0, stream, mid, mw2, ppart);
        hipLaunchKernelGGL(k_mut2c, dim3(KSEL * H / 256), dim3(256), 0, stream,
                           ppart, mb2, bp, mask, mflag, out_off);
    } else {
        // fallback: round-1 proven path
        float* xpart = (float*)ws;
        int*   best  = (int*)(ws + (size_t)NPOP * 8 * 4);
        int*   mflag = (int*)(ws + (size_t)NPOP * 8 * 4 + 256);
        float* mid   = (float*)(ws + (size_t)NPOP * 8 * 4 + 512);

        hipLaunchKernelGGL(k_maskdetect, dim3(1), dim3(256), 0, stream,
                           (const unsigned int*)mask, mflag);
        hipLaunchKernelGGL(k_fit_gemm, dim3(8, 512), dim3(256), 0, stream,
                           pop, sw1, sb1, sw2, xpart);
        hipLaunchKernelGGL(k_fit_finish8, dim3(NPOP / 256), dim3(256), 0, stream,
                           xpart, sb2, out_fit);
        hipLaunchKernelGGL(k_topk3, dim3(1), dim3(1024), 0, stream, out_fit, best);
        hipLaunchKernelGGL(k_mut1, dim3(H / 64), dim3(256), 0, stream,
                           pop, best, mw1, mb1, mid);
        hipLaunchKernelGGL(k_mut2, dim3(H / 64), dim3(256), 0, stream,
                           mid, mw2, mb2, pop, best, mask, mflag, out_off);
    }
}